// Round 1
// baseline (2481.900 us; speedup 1.0000x reference)
//
#include <hip/hip_runtime.h>
#include <hip/hip_bf16.h>

// Sinkhorn entropic OT (reg=1, 100 iters) between x[4096,1024], y[4096,1024] fp32.
// value = sum_i f_i r_i + sum_j g_j c_j   (the <P,C> and KL C-terms cancel exactly)
// After final g-update: c_j = 1/n exactly; r_i = (1/n) * 2^(phi_i - phi'_i) with
// phi' = one extra f-update. All math in base-2 log domain:
//   S_ij  = C_ij * log2(e)/reg              (fp32, stored, 64MB; ST also stored)
//   phi_i = f_i*log2e/reg + log2(a_i),  gamma_j = g_j*log2e/reg + log2(b_j)
//   f-update:  phi_i  = -log2( sum_j 2^(gamma_j - S_ij) )  - 12
//   g-update:  gamma_j= -log2( sum_i 2^(phi_i  - ST_ji) )  - 12
// out = value / d = ln2/(4096*1024) * [ sum_i 2^(phi-phi')*(phi+12) + sum_j (gamma+12) ]

#define N 4096
#define D 1024
#define L2E 1.4426950408889634f
#define LOG2A (-12.0f)   // log2(1/4096)

typedef unsigned short u16;
typedef __attribute__((ext_vector_type(8))) short bf16x8;
typedef __attribute__((ext_vector_type(4))) float f32x4;

static __device__ inline u16 f2bf(float f) {
  unsigned u = __float_as_uint(f);
  unsigned r = (u + 0x7FFFu + ((u >> 16) & 1u)) >> 16;
  return (u16)r;
}

static __device__ inline void gload_lds16(const void* g, void* l) {
  __builtin_amdgcn_global_load_lds(
      (const __attribute__((address_space(1))) void*)g,
      (__attribute__((address_space(3))) void*)l, 16, 0, 0);
}

// ---- prep: row sum-of-squares (scaled by log2e) + fp32->bf16 conversion + gamma init
__global__ __launch_bounds__(256) void prep_kernel(
    const float* __restrict__ x, const float* __restrict__ y,
    u16* __restrict__ xb, u16* __restrict__ yb,
    float* __restrict__ sxL, float* __restrict__ syL, float* __restrict__ gamma)
{
  int rb = blockIdx.x;                 // 0..8191
  bool isY = rb >= N;
  int row = isY ? rb - N : rb;
  const float4* src = (const float4*)((isY ? y : x) + (size_t)row * D);
  u16* dst = (isY ? yb : xb) + (size_t)row * D;
  int t = threadIdx.x;

  float4 v = src[t];
  float ss = v.x * v.x + v.y * v.y + v.z * v.z + v.w * v.w;
  ushort4 h;
  h.x = f2bf(v.x); h.y = f2bf(v.y); h.z = f2bf(v.z); h.w = f2bf(v.w);
  ((ushort4*)dst)[t] = h;

  #pragma unroll
  for (int o = 1; o < 64; o <<= 1) ss += __shfl_xor(ss, o, 64);
  __shared__ float sred[4];
  if ((t & 63) == 0) sred[t >> 6] = ss;
  __syncthreads();
  if (t == 0) {
    float tot = sred[0] + sred[1] + sred[2] + sred[3];
    (isY ? syL : sxL)[row] = tot * L2E;
    if (isY) gamma[row] = LOG2A;       // g=0 -> gamma = log2(b) = -12
  }
}

// ---- GEMM: out[i][j] = saL[i] + sbL[j] - 2*log2e * (A_i . B_j), bf16 MFMA 128x128 tile
__global__ __launch_bounds__(256) void gemm_s(
    const u16* __restrict__ A, const u16* __restrict__ B,
    const float* __restrict__ saL, const float* __restrict__ sbL,
    float* __restrict__ out)
{
  __shared__ u16 As[128 * 64];
  __shared__ u16 Bs[128 * 64];
  const int t = threadIdx.x;
  const int lane = t & 63, w = t >> 6;
  const int wm = w >> 1, wn = w & 1;          // 2x2 wave grid, 64x64 per wave
  const int i0 = blockIdx.y * 128, j0 = blockIdx.x * 128;

  f32x4 acc[4][4] = {};

  for (int k0 = 0; k0 < D; k0 += 64) {
    #pragma unroll
    for (int q = 0; q < 4; ++q) {
      int lin = q * 256 + t;
      int row = lin >> 3, c8 = lin & 7;
      int cs = c8 ^ (row & 7);               // pre-swizzled global source (linear LDS dest)
      const u16* ga = A + (size_t)(i0 + row) * D + k0 + cs * 8;
      const u16* gb = B + (size_t)(j0 + row) * D + k0 + cs * 8;
      char* la = ((char*)As) + q * 4096 + w * 1024;
      char* lb = ((char*)Bs) + q * 4096 + w * 1024;
      gload_lds16(ga, la);
      gload_lds16(gb, lb);
    }
    __syncthreads();
    #pragma unroll
    for (int kk = 0; kk < 2; ++kk) {
      bf16x8 af[4], bf[4];
      const int g = lane >> 4;
      #pragma unroll
      for (int fm = 0; fm < 4; ++fm) {
        int r = wm * 64 + fm * 16 + (lane & 15);
        int off = r * 128 + (((kk * 4 + g) ^ (r & 7)) * 16);
        af[fm] = *(const bf16x8*)(((const char*)As) + off);
      }
      #pragma unroll
      for (int fn = 0; fn < 4; ++fn) {
        int r = wn * 64 + fn * 16 + (lane & 15);
        int off = r * 128 + (((kk * 4 + g) ^ (r & 7)) * 16);
        bf[fn] = *(const bf16x8*)(((const char*)Bs) + off);
      }
      #pragma unroll
      for (int fm = 0; fm < 4; ++fm)
        #pragma unroll
        for (int fn = 0; fn < 4; ++fn)
          acc[fm][fn] = __builtin_amdgcn_mfma_f32_16x16x32_bf16(af[fm], bf[fn], acc[fm][fn], 0, 0, 0);
    }
    __syncthreads();
  }

  const float TWO_L2E = 2.0f * L2E;
  #pragma unroll
  for (int fm = 0; fm < 4; ++fm) {
    #pragma unroll
    for (int fn = 0; fn < 4; ++fn) {
      int gj = j0 + wn * 64 + fn * 16 + (lane & 15);
      #pragma unroll
      for (int r = 0; r < 4; ++r) {
        int gi = i0 + wm * 64 + fm * 16 + (lane >> 4) * 4 + r;
        out[(size_t)gi * N + gj] = saL[gi] + sbL[gj] - TWO_L2E * acc[fm][fn][r];
      }
    }
  }
}

// ---- row logsumexp update: dout[i] = -(max + log2 sum_j 2^(din[j]-M[i][j])) + log2w
__global__ __launch_bounds__(256) void lse_row(
    const float* __restrict__ Mrow, const float* __restrict__ din,
    float* __restrict__ dout, float log2w)
{
  const int i = blockIdx.x;
  const float4* row = (const float4*)(Mrow + (size_t)i * N);
  const float4* dv = (const float4*)din;
  const int t = threadIdx.x;

  float v[16];
  float mx = -3.0e38f;
  #pragma unroll
  for (int k = 0; k < 4; ++k) {
    float4 s4 = row[t + 256 * k];
    float4 d4 = dv[t + 256 * k];
    v[4 * k + 0] = d4.x - s4.x;
    v[4 * k + 1] = d4.y - s4.y;
    v[4 * k + 2] = d4.z - s4.z;
    v[4 * k + 3] = d4.w - s4.w;
    mx = fmaxf(mx, fmaxf(fmaxf(v[4 * k], v[4 * k + 1]), fmaxf(v[4 * k + 2], v[4 * k + 3])));
  }
  float s = 0.0f;
  #pragma unroll
  for (int k = 0; k < 16; ++k) s += exp2f(v[k] - mx);

  #pragma unroll
  for (int o = 1; o < 64; o <<= 1) {
    float mo = __shfl_xor(mx, o, 64);
    float so = __shfl_xor(s, o, 64);
    float mn = fmaxf(mx, mo);
    s = s * exp2f(mx - mn) + so * exp2f(mo - mn);
    mx = mn;
  }
  __shared__ float sm[4], ssum[4];
  if ((t & 63) == 0) { sm[t >> 6] = mx; ssum[t >> 6] = s; }
  __syncthreads();
  if (t == 0) {
    float M0 = fmaxf(fmaxf(sm[0], sm[1]), fmaxf(sm[2], sm[3]));
    float S0 = ssum[0] * exp2f(sm[0] - M0) + ssum[1] * exp2f(sm[1] - M0)
             + ssum[2] * exp2f(sm[2] - M0) + ssum[3] * exp2f(sm[3] - M0);
    dout[i] = -(M0 + log2f(S0)) + log2w;
  }
}

// ---- final reduction: out = ln2/(4096*1024) * [sum 2^(phi-phip)*(phi+12) + sum (gamma+12)]
__global__ __launch_bounds__(256) void finalize(
    const float* __restrict__ phi, const float* __restrict__ phip,
    const float* __restrict__ gamma, float* __restrict__ out)
{
  int t = threadIdx.x;
  float acc = 0.0f;
  for (int i = t; i < N; i += 256) {
    float p = phi[i];
    acc += exp2f(p - phip[i]) * (p - LOG2A);
    acc += gamma[i] - LOG2A;
  }
  #pragma unroll
  for (int o = 1; o < 64; o <<= 1) acc += __shfl_xor(acc, o, 64);
  __shared__ float sr[4];
  if ((t & 63) == 0) sr[t >> 6] = acc;
  __syncthreads();
  if (t == 0) {
    float tot = sr[0] + sr[1] + sr[2] + sr[3];
    const float LN2 = 0.6931471805599453f;
    out[0] = tot * (LN2 / ((float)N * (float)D));
  }
}

extern "C" void kernel_launch(void* const* d_in, const int* in_sizes, int n_in,
                              void* d_out, int out_size, void* d_ws, size_t ws_size,
                              hipStream_t stream) {
  const float* x = (const float*)d_in[0];
  const float* y = (const float*)d_in[1];
  float* out = (float*)d_out;
  char* ws = (char*)d_ws;

  const size_t SZ_MAT = (size_t)N * N * sizeof(float);      // 64 MiB
  const size_t SZ_BF  = (size_t)N * D * sizeof(u16);        // 8 MiB
  float* S   = (float*)(ws);
  float* ST  = (float*)(ws + SZ_MAT);
  u16*   xb  = (u16*)  (ws + 2 * SZ_MAT);
  u16*   yb  = (u16*)  (ws + 2 * SZ_MAT + SZ_BF);
  float* sxL = (float*)(ws + 2 * SZ_MAT + 2 * SZ_BF);
  float* syL = (float*)(ws + 2 * SZ_MAT + 2 * SZ_BF + 16384);
  float* phi = (float*)(ws + 2 * SZ_MAT + 2 * SZ_BF + 2 * 16384);
  float* gam = (float*)(ws + 2 * SZ_MAT + 2 * SZ_BF + 3 * 16384);
  float* php = (float*)(ws + 2 * SZ_MAT + 2 * SZ_BF + 4 * 16384);

  prep_kernel<<<2 * N / 1, 256, 0, stream>>>(x, y, xb, yb, sxL, syL, gam);

  dim3 gg(N / 128, N / 128, 1);
  gemm_s<<<gg, 256, 0, stream>>>(xb, yb, sxL, syL, S);    // S[i][j]
  gemm_s<<<gg, 256, 0, stream>>>(yb, xb, syL, sxL, ST);   // ST[j][i] = S[i][j]

  for (int it = 0; it < 100; ++it) {
    lse_row<<<N, 256, 0, stream>>>(S,  gam, phi, LOG2A);  // f-update
    lse_row<<<N, 256, 0, stream>>>(ST, phi, gam, LOG2A);  // g-update
  }
  lse_row<<<N, 256, 0, stream>>>(S, gam, php, LOG2A);     // extra f-update for row marginals

  finalize<<<1, 256, 0, stream>>>(phi, php, gam, out);
}

// Round 2
// 2229.585 us; speedup vs baseline: 1.1132x; 1.1132x over previous
//
#include <hip/hip_runtime.h>
#include <hip/hip_bf16.h>

// Sinkhorn entropic OT (reg=1, 100 iters) between x[4096,1024], y[4096,1024] fp32.
// value = sum_i f_i r_i + sum_j g_j c_j  (exact for any f,g — C-terms cancel).
// Base-2 log domain, centered fp16 cost matrix:
//   S_ij = ax_i + ay_j - Z_ij,  Z = 2*log2e*(x_i . y_j)  [fp16, 32MiB, ZT too]
//   ax_i = log2e*||x_i||^2, ay_j = log2e*||y_j||^2       [fp32 vectors]
// Updates telescope on "cores":
//   f: core_i = -log2 sum_j 2^(u_j + Z_ij) + LOG2A ;  phi_i = core_i + ax_i ; next w = core
//   g: core_j = -log2 sum_i 2^(w_i + ZT_ji) + LOG2A;  gam_j = core_j + ay_j ; next u = core
//   init u_j = LOG2A - ay_j   (g=0)
// out = ln2/(N*D) * [ sum_i 2^(phi-php)*(phi-LOG2A) + sum_j (gam-LOG2A) ]

#define N 4096
#define D 1024
#define L2E 1.4426950408889634f
#define LOG2A (-12.0f)   // log2(1/4096)

typedef unsigned short u16;
typedef _Float16 f16;
typedef __attribute__((ext_vector_type(8))) short bf16x8;
typedef __attribute__((ext_vector_type(8))) _Float16 f16x8;
typedef __attribute__((ext_vector_type(4))) float f32x4;

static __device__ inline u16 f2bf(float f) {
  unsigned u = __float_as_uint(f);
  unsigned r = (u + 0x7FFFu + ((u >> 16) & 1u)) >> 16;
  return (u16)r;
}

static __device__ inline void gload_lds16(const void* g, void* l) {
  __builtin_amdgcn_global_load_lds(
      (const __attribute__((address_space(1))) void*)g,
      (__attribute__((address_space(3))) void*)l, 16, 0, 0);
}

// ---- prep: row sum-of-squares + fp32->bf16 conversion + ax/ay/u0
__global__ __launch_bounds__(256) void prep_kernel(
    const float* __restrict__ x, const float* __restrict__ y,
    u16* __restrict__ xb, u16* __restrict__ yb,
    float* __restrict__ ax, float* __restrict__ ay, float* __restrict__ u0)
{
  int rb = blockIdx.x;                 // 0..8191
  bool isY = rb >= N;
  int row = isY ? rb - N : rb;
  const float4* src = (const float4*)((isY ? y : x) + (size_t)row * D);
  u16* dst = (isY ? yb : xb) + (size_t)row * D;
  int t = threadIdx.x;

  float4 v = src[t];
  float ss = v.x * v.x + v.y * v.y + v.z * v.z + v.w * v.w;
  ushort4 h;
  h.x = f2bf(v.x); h.y = f2bf(v.y); h.z = f2bf(v.z); h.w = f2bf(v.w);
  ((ushort4*)dst)[t] = h;

  #pragma unroll
  for (int o = 1; o < 64; o <<= 1) ss += __shfl_xor(ss, o, 64);
  __shared__ float sred[4];
  if ((t & 63) == 0) sred[t >> 6] = ss;
  __syncthreads();
  if (t == 0) {
    float a = (sred[0] + sred[1] + sred[2] + sred[3]) * L2E;
    if (isY) { ay[row] = a; u0[row] = LOG2A - a; }
    else     { ax[row] = a; }
  }
}

// ---- GEMM: Z[i][j] = fp16( 2*log2e * (A_i . B_j) ), bf16 MFMA 128x128 tile
__global__ __launch_bounds__(256) void gemm_s(
    const u16* __restrict__ A, const u16* __restrict__ B, f16* __restrict__ out)
{
  __shared__ u16 As[128 * 64];
  __shared__ u16 Bs[128 * 64];
  const int t = threadIdx.x;
  const int lane = t & 63, w = t >> 6;
  const int wm = w >> 1, wn = w & 1;          // 2x2 wave grid, 64x64 per wave
  const int i0 = blockIdx.y * 128, j0 = blockIdx.x * 128;

  f32x4 acc[4][4] = {};

  for (int k0 = 0; k0 < D; k0 += 64) {
    #pragma unroll
    for (int q = 0; q < 4; ++q) {
      int lin = q * 256 + t;
      int row = lin >> 3, c8 = lin & 7;
      int cs = c8 ^ (row & 7);               // pre-swizzled global source (linear LDS dest)
      const u16* ga = A + (size_t)(i0 + row) * D + k0 + cs * 8;
      const u16* gb = B + (size_t)(j0 + row) * D + k0 + cs * 8;
      char* la = ((char*)As) + q * 4096 + w * 1024;
      char* lb = ((char*)Bs) + q * 4096 + w * 1024;
      gload_lds16(ga, la);
      gload_lds16(gb, lb);
    }
    __syncthreads();
    #pragma unroll
    for (int kk = 0; kk < 2; ++kk) {
      bf16x8 af[4], bfr[4];
      const int g = lane >> 4;
      #pragma unroll
      for (int fm = 0; fm < 4; ++fm) {
        int r = wm * 64 + fm * 16 + (lane & 15);
        int off = r * 128 + (((kk * 4 + g) ^ (r & 7)) * 16);
        af[fm] = *(const bf16x8*)(((const char*)As) + off);
      }
      #pragma unroll
      for (int fn = 0; fn < 4; ++fn) {
        int r = wn * 64 + fn * 16 + (lane & 15);
        int off = r * 128 + (((kk * 4 + g) ^ (r & 7)) * 16);
        bfr[fn] = *(const bf16x8*)(((const char*)Bs) + off);
      }
      #pragma unroll
      for (int fm = 0; fm < 4; ++fm)
        #pragma unroll
        for (int fn = 0; fn < 4; ++fn)
          acc[fm][fn] = __builtin_amdgcn_mfma_f32_16x16x32_bf16(af[fm], bfr[fn], acc[fm][fn], 0, 0, 0);
    }
    __syncthreads();
  }

  const float TWO_L2E = 2.0f * L2E;
  #pragma unroll
  for (int fm = 0; fm < 4; ++fm) {
    #pragma unroll
    for (int fn = 0; fn < 4; ++fn) {
      int gj = j0 + wn * 64 + fn * 16 + (lane & 15);
      #pragma unroll
      for (int r = 0; r < 4; ++r) {
        int gi = i0 + wm * 64 + fm * 16 + (lane >> 4) * 4 + r;
        out[(size_t)gi * N + gj] = (f16)(TWO_L2E * acc[fm][fn][r]);
      }
    }
  }
}

// ---- row LSE over fp16 matrix, 2 rows per block:
// core = -log2 sum_j 2^(u_j + Z_ij) + LOG2A ; outMain = core + offv[row]; outNext = core
__global__ __launch_bounds__(256) void lse2(
    const f16* __restrict__ Zm, const float* __restrict__ u,
    const float* __restrict__ offv,
    float* __restrict__ outMain, float* __restrict__ outNext)
{
  const int t = threadIdx.x;

  // thread t owns columns j in {8t..8t+7} U {2048+8t..2048+8t+7}
  float uu[16];
  {
    const float4* uv = (const float4*)u;
    float4 a = uv[2 * t], b = uv[2 * t + 1];
    float4 c = uv[512 + 2 * t], d = uv[512 + 2 * t + 1];
    uu[0] = a.x; uu[1] = a.y; uu[2]  = a.z; uu[3]  = a.w;
    uu[4] = b.x; uu[5] = b.y; uu[6]  = b.z; uu[7]  = b.w;
    uu[8] = c.x; uu[9] = c.y; uu[10] = c.z; uu[11] = c.w;
    uu[12] = d.x; uu[13] = d.y; uu[14] = d.z; uu[15] = d.w;
  }

  __shared__ float sm[2][4], sb[2][4];

  #pragma unroll
  for (int r = 0; r < 2; ++r) {
    const int row = (blockIdx.x << 1) + r;
    const f16x8* zr = (const f16x8*)(Zm + (size_t)row * N);
    f16x8 z0 = zr[t], z1 = zr[256 + t];
    float v[16];
    float mx = -3.0e38f;
    #pragma unroll
    for (int q = 0; q < 8; ++q) {
      v[q]     = uu[q]     + (float)z0[q];
      v[8 + q] = uu[8 + q] + (float)z1[q];
    }
    #pragma unroll
    for (int q = 0; q < 16; ++q) mx = fmaxf(mx, v[q]);
    float s = 0.0f;
    #pragma unroll
    for (int q = 0; q < 16; ++q) s += exp2f(v[q] - mx);

    #pragma unroll
    for (int o = 1; o < 64; o <<= 1) {
      float mo = __shfl_xor(mx, o, 64);
      float so = __shfl_xor(s, o, 64);
      float mn = fmaxf(mx, mo);
      s = s * exp2f(mx - mn) + so * exp2f(mo - mn);
      mx = mn;
    }
    if ((t & 63) == 0) { sm[r][t >> 6] = mx; sb[r][t >> 6] = s; }
  }
  __syncthreads();
  if (t < 2) {
    const int row = (blockIdx.x << 1) + t;
    float M0 = fmaxf(fmaxf(sm[t][0], sm[t][1]), fmaxf(sm[t][2], sm[t][3]));
    float S0 = sb[t][0] * exp2f(sm[t][0] - M0) + sb[t][1] * exp2f(sm[t][1] - M0)
             + sb[t][2] * exp2f(sm[t][2] - M0) + sb[t][3] * exp2f(sm[t][3] - M0);
    float core = -(M0 + log2f(S0)) + LOG2A;
    outMain[row] = core + offv[row];
    outNext[row] = core;
  }
}

// ---- final reduction: out = ln2/(N*D) * [sum 2^(phi-php)*(phi-LOG2A) + sum (gam-LOG2A)]
__global__ __launch_bounds__(256) void finalize(
    const float* __restrict__ phi, const float* __restrict__ php,
    const float* __restrict__ gam, float* __restrict__ out)
{
  int t = threadIdx.x;
  float acc = 0.0f;
  for (int i = t; i < N; i += 256) {
    float p = phi[i];
    acc += exp2f(p - php[i]) * (p - LOG2A);
    acc += gam[i] - LOG2A;
  }
  #pragma unroll
  for (int o = 1; o < 64; o <<= 1) acc += __shfl_xor(acc, o, 64);
  __shared__ float sr[4];
  if ((t & 63) == 0) sr[t >> 6] = acc;
  __syncthreads();
  if (t == 0) {
    float tot = sr[0] + sr[1] + sr[2] + sr[3];
    const float LN2 = 0.6931471805599453f;
    out[0] = tot * (LN2 / ((float)N * (float)D));
  }
}

extern "C" void kernel_launch(void* const* d_in, const int* in_sizes, int n_in,
                              void* d_out, int out_size, void* d_ws, size_t ws_size,
                              hipStream_t stream) {
  const float* x = (const float*)d_in[0];
  const float* y = (const float*)d_in[1];
  float* out = (float*)d_out;
  char* ws = (char*)d_ws;

  const size_t SZ_Z  = (size_t)N * N * sizeof(f16);   // 32 MiB
  const size_t SZ_BF = (size_t)N * D * sizeof(u16);   // 8 MiB
  const size_t SZ_V  = (size_t)N * sizeof(float);     // 16 KiB

  f16* Z   = (f16*)(ws);
  f16* ZT  = (f16*)(ws + SZ_Z);
  u16* xb  = (u16*)(ws + 2 * SZ_Z);
  u16* yb  = (u16*)(ws + 2 * SZ_Z + SZ_BF);
  char* vb = ws + 2 * SZ_Z + 2 * SZ_BF;
  float* ax  = (float*)(vb + 0 * SZ_V);
  float* ay  = (float*)(vb + 1 * SZ_V);
  float* u   = (float*)(vb + 2 * SZ_V);
  float* w   = (float*)(vb + 3 * SZ_V);
  float* phi = (float*)(vb + 4 * SZ_V);
  float* gam = (float*)(vb + 5 * SZ_V);
  float* php = (float*)(vb + 6 * SZ_V);

  prep_kernel<<<2 * N, 256, 0, stream>>>(x, y, xb, yb, ax, ay, u);

  dim3 gg(N / 128, N / 128, 1);
  gemm_s<<<gg, 256, 0, stream>>>(xb, yb, Z);    // Z[i][j]
  gemm_s<<<gg, 256, 0, stream>>>(yb, xb, ZT);   // ZT[j][i] = Z[i][j]

  for (int it = 0; it < 100; ++it) {
    lse2<<<N / 2, 256, 0, stream>>>(Z,  u, ax, phi, w);   // f-update
    lse2<<<N / 2, 256, 0, stream>>>(ZT, w, ay, gam, u);   // g-update
  }
  lse2<<<N / 2, 256, 0, stream>>>(Z, u, ax, php, w);      // extra f for row marginals

  finalize<<<1, 256, 0, stream>>>(phi, php, gam, out);
}